// Round 3
// baseline (499.531 us; speedup 1.0000x reference)
//
#include <hip/hip_runtime.h>

// Problem constants
#define B_     32
#define NOTES_ 78
#define T_     128
#define IN_    80
#define H_     128
#define NSEQ_  (B_*NOTES_)    // 2496
#define MBLK   16             // sequences per block (A-tile rows of 16x16x32 MFMA)
#define NBLK1  (NSEQ_/MBLK)   // 156 blocks (hard cap: recurrence keeps a 16-seq tile per block)
#define SEQ2_  (B_*T_)        // 4096 note-LSTM sequences
#define SHSTR  136            // sH row stride in shorts (W=68 words == 4 mod 32: tiled banks)

typedef __attribute__((ext_vector_type(8))) short short8;   // 8 x bf16 (4 VGPRs)
typedef __attribute__((ext_vector_type(4))) float f32x4;

__device__ __forceinline__ unsigned short f2bf(float f) {
    unsigned u; __builtin_memcpy(&u, &f, 4);
    u += 0x7fffu + ((u >> 16) & 1u);          // RNE
    return (unsigned short)(u >> 16);
}
__device__ __forceinline__ short8 pack8(const float* p) {   // scalar (init-time only)
    short8 r;
    #pragma unroll
    for (int k = 0; k < 8; ++k) r[k] = (short)f2bf(p[k]);
    return r;
}
__device__ __forceinline__ short8 pack8v(f32x4 a, f32x4 b) { // vector-load variant
    short8 r;
    #pragma unroll
    for (int k = 0; k < 4; ++k) { r[k] = (short)f2bf(a[k]); r[4+k] = (short)f2bf(b[k]); }
    return r;
}
// v_rcp_f32 instead of the full-precision divide sequence: ~1ulp, far inside
// the bf16-dominated error budget.
__device__ __forceinline__ float rcpf(float x)  { return __builtin_amdgcn_rcpf(x); }
__device__ __forceinline__ float sigm(float x)  { return rcpf(1.f + __expf(-x)); }
__device__ __forceinline__ float tanh_(float x) { return 2.f * rcpf(1.f + __expf(-2.f*x)) - 1.f; }

// ---------------------------------------------------------------------------
// Fused time LSTM + note-gate pre-activations.  8 waves / 512 thr / block;
// 16 sequences per block; 156 blocks (grid capped by the recurrence =>
// latency-bound: total time = 128 x step critical path).
//
// THIS ROUND: __launch_bounds__(512, 1).  The previous (512, 2) made the
// allocator target 128 VGPRs while ~210 are live (weights wf/hf/wn = 128
// VGPRs alone) -> every step reloaded spilled weight fragments from scratch.
// A 512-thr block caps VGPRs at 256 anyway (8 waves must be co-resident), so
// occupancy is unchanged (2 waves/SIMD) and the spills simply vanish.
// Also fused: x f32->bf16 conversion moved into the prefetch (vectorized
// f32x4 loads) -- kills the separate xcvt dispatch and 102 MB of xb traffic.
//
// Step pipeline:
//   - accX[g] = bias + x(t+1).Wih^T computed during step t (off critical path)
//   - step t's gates start from C-input accX -> h-dependent chain is 4 MFMAs
//   - x(t+2) prefetched with a full-step window
//   - Gn duty (note-LSTM pre-activations from h(t-1)) rotates across waves
//   - ONE raw s_barrier per step, lgkmcnt(0) only (global traffic never
//     drains at the barrier); sH double-buffered so one barrier is race-free
// ---------------------------------------------------------------------------
__global__ __launch_bounds__(512, 1) void time_lstm_kernel(
    const float* __restrict__ x,     // [NSEQ][T][IN] f32
    const float* __restrict__ Wih,   // [512][80]  f32
    const float* __restrict__ Whh,   // [512][128] f32
    const float* __restrict__ bih,   // [512] f32
    const float* __restrict__ bhh,   // [512] f32
    const float* __restrict__ Wn,    // [8][128] f32 (Wih_n)
    const float* __restrict__ bn1,   // [8] f32
    const float* __restrict__ bn2,   // [8] f32
    float* __restrict__ Gn)          // [B*T][NOTES][8] f32 (ws)
{
    __shared__ unsigned short sH[2][MBLK * SHSTR];   // 8.7 KB total

    const int tid  = threadIdx.x;
    const int wave = tid >> 6, lane = tid & 63;
    const int m16  = lane & 15, quad = lane >> 4;
    const int seq0 = blockIdx.x * MBLK;
    const int j    = wave * 16 + m16;          // this lane's h-column

    for (int i = tid; i < 2 * MBLK * SHSTR; i += 512)
        ((unsigned short*)sH)[i] = 0;          // h(-1) = 0

    // ---- weight B-fragments (f32 -> bf16): 4 gates x (3 Wih + 4 Whh) ----
    const short8 zero8 = (short8){0,0,0,0,0,0,0,0};
    short8 wf[4][3], hf[4][4];
    #pragma unroll
    for (int g = 0; g < 4; ++g) {
        const int n = g * H_ + j;              // gate column in [0,512)
        #pragma unroll
        for (int kt = 0; kt < 3; ++kt) {
            const int k = kt * 32 + quad * 8;
            wf[g][kt] = (k < IN_) ? pack8(Wih + n * IN_ + k) : zero8;
        }
        #pragma unroll
        for (int kt = 0; kt < 4; ++kt)
            hf[g][kt] = pack8(Whh + n * H_ + kt * 32 + quad * 8);
    }

    // ---- note-gate fragments + output addressing (ALL waves: Gn rotates) ----
    short8 wn[4];
    #pragma unroll
    for (int kt = 0; kt < 4; ++kt)
        wn[kt] = (m16 < 8) ? pack8(Wn + m16 * H_ + kt * 32 + quad * 8) : zero8;
    const float bns = (m16 < 8) ? (bn1[m16] + bn2[m16]) : 0.f;
    unsigned gbase[4];
    #pragma unroll
    for (int r = 0; r < 4; ++r) {
        const int sq = seq0 + quad * 4 + r;
        const int bb = sq / NOTES_;
        const int nn = sq - bb * NOTES_;
        gbase[r] = ((unsigned)bb * (T_ * NOTES_) + (unsigned)nn) * 8u + (unsigned)m16;
    }

    // ---- per-lane biases for column j (folded into accX init below) ----
    float bg4[4];
    #pragma unroll
    for (int g = 0; g < 4; ++g) bg4[g] = bih[g * H_ + j] + bhh[g * H_ + j];

    // ---- x row pointer (lane m16 -> sequence row) ----
    const float* xr = x + (size_t)(seq0 + m16) * T_ * IN_;

    short8 ax0, ax1, ax2 = zero8;
    {   // load x(0), vectorized
        const float* p = xr;
        ax0 = pack8v(*(const f32x4*)(p + quad * 8),      *(const f32x4*)(p + quad * 8 + 4));
        ax1 = pack8v(*(const f32x4*)(p + 32 + quad * 8), *(const f32x4*)(p + 32 + quad * 8 + 4));
        if (quad < 2)
            ax2 = pack8v(*(const f32x4*)(p + 64 + quad * 8), *(const f32x4*)(p + 64 + quad * 8 + 4));
    }

    // prologue: accX(0) = bias + x(0).Wih^T
    f32x4 accX[4];
    #pragma unroll
    for (int g = 0; g < 4; ++g) {
        accX[g] = (f32x4){bg4[g], bg4[g], bg4[g], bg4[g]};
        accX[g] = __builtin_amdgcn_mfma_f32_16x16x32_bf16(ax0, wf[g][0], accX[g], 0, 0, 0);
        accX[g] = __builtin_amdgcn_mfma_f32_16x16x32_bf16(ax1, wf[g][1], accX[g], 0, 0, 0);
        accX[g] = __builtin_amdgcn_mfma_f32_16x16x32_bf16(ax2, wf[g][2], accX[g], 0, 0, 0);
    }
    {   // load x(1)
        const float* p = xr + IN_;
        ax0 = pack8v(*(const f32x4*)(p + quad * 8),      *(const f32x4*)(p + quad * 8 + 4));
        ax1 = pack8v(*(const f32x4*)(p + 32 + quad * 8), *(const f32x4*)(p + 32 + quad * 8 + 4));
        if (quad < 2)
            ax2 = pack8v(*(const f32x4*)(p + 64 + quad * 8), *(const f32x4*)(p + 64 + quad * 8 + 4));
    }

    float cst[4] = {0.f, 0.f, 0.f, 0.f};       // cell state, in-register

    __syncthreads();                            // init fence (once; full drain ok)

    for (int t = 0; t < T_; ++t) {
        const unsigned short* sHr = sH[t & 1];          // holds h(t-1)
        unsigned short*       sHw = sH[(t & 1) ^ 1];    // receives h(t)

        // h(t-1) A-fragments (identical across waves)
        short8 ah[4];
        #pragma unroll
        for (int kt = 0; kt < 4; ++kt)
            ah[kt] = *(const short8*)(sHr + m16 * SHSTR + kt * 32 + quad * 8);

        // main gate MFMAs: start from accX (bias + x-part), 4-deep h chain
        f32x4 acc[4];
        #pragma unroll
        for (int g = 0; g < 4; ++g) {
            acc[g] = accX[g];
            #pragma unroll
            for (int kt = 0; kt < 4; ++kt)
                acc[g] = __builtin_amdgcn_mfma_f32_16x16x32_bf16(ah[kt], hf[g][kt], acc[g], 0, 0, 0);
        }

        // note-gate tile for step t-1 (rotating wave; uses same ah)
        if (t > 0 && wave == ((t - 1) & 7)) {
            f32x4 an = (f32x4){0.f, 0.f, 0.f, 0.f};
            #pragma unroll
            for (int kt = 0; kt < 4; ++kt)
                an = __builtin_amdgcn_mfma_f32_16x16x32_bf16(ah[kt], wn[kt], an, 0, 0, 0);
            if (m16 < 8) {
                #pragma unroll
                for (int r = 0; r < 4; ++r)
                    Gn[gbase[r] + (unsigned)(t - 1) * (NOTES_ * 8)] = an[r] + bns;
            }
        }

        // accX(t+1) = bias + x(t+1).Wih^T  -- off critical path (no h dep)
        if (t + 1 < T_) {
            #pragma unroll
            for (int g = 0; g < 4; ++g) {
                accX[g] = (f32x4){bg4[g], bg4[g], bg4[g], bg4[g]};
                accX[g] = __builtin_amdgcn_mfma_f32_16x16x32_bf16(ax0, wf[g][0], accX[g], 0, 0, 0);
                accX[g] = __builtin_amdgcn_mfma_f32_16x16x32_bf16(ax1, wf[g][1], accX[g], 0, 0, 0);
                accX[g] = __builtin_amdgcn_mfma_f32_16x16x32_bf16(ax2, wf[g][2], accX[g], 0, 0, 0);
            }
        }

        // prefetch x(t+2) as f32 (vectorized), pack to bf16 in-register:
        // consumed next step by the accX MFMAs (full-step window); never
        // drained at the barrier (lgkmcnt-only wait below)
        if (t + 2 < T_) {
            const float* p = xr + (t + 2) * IN_;
            ax0 = pack8v(*(const f32x4*)(p + quad * 8),      *(const f32x4*)(p + quad * 8 + 4));
            ax1 = pack8v(*(const f32x4*)(p + 32 + quad * 8), *(const f32x4*)(p + 32 + quad * 8 + 4));
            if (quad < 2)
                ax2 = pack8v(*(const f32x4*)(p + 64 + quad * 8), *(const f32x4*)(p + 64 + quad * 8 + 4));
        }

        // in-register LSTM cell update: lane holds i,f,g,o for 4 seqs at col j
        // (biases already inside acc via accX init)
        #pragma unroll
        for (int r = 0; r < 4; ++r) {
            const float cf = sigm(acc[1][r]) * cst[r] + sigm(acc[0][r]) * tanh_(acc[2][r]);
            cst[r] = cf;
            const float h = sigm(acc[3][r]) * tanh_(cf);
            sHw[(quad * 4 + r) * SHSTR + j] = f2bf(h);
        }

        // ONE barrier per step; double-buffered sH makes it race-free.
        // sched_barrier pins ds ops around the asm waitcnt (guide rule #18).
        __builtin_amdgcn_sched_barrier(0);
        asm volatile("s_waitcnt lgkmcnt(0)" ::: "memory");
        __builtin_amdgcn_s_barrier();
        __builtin_amdgcn_sched_barrier(0);
    }

    // epilogue: note-gate tile for t = T-1 (h(127) sits in sH[0])
    if (wave == ((T_ - 1) & 7)) {
        const unsigned short* sHr = sH[T_ & 1];
        short8 ah[4];
        #pragma unroll
        for (int kt = 0; kt < 4; ++kt)
            ah[kt] = *(const short8*)(sHr + m16 * SHSTR + kt * 32 + quad * 8);
        f32x4 an = (f32x4){0.f, 0.f, 0.f, 0.f};
        #pragma unroll
        for (int kt = 0; kt < 4; ++kt)
            an = __builtin_amdgcn_mfma_f32_16x16x32_bf16(ah[kt], wn[kt], an, 0, 0, 0);
        if (m16 < 8) {
            #pragma unroll
            for (int r = 0; r < 4; ++r)
                Gn[gbase[r] + (unsigned)(T_ - 1) * (NOTES_ * 8)] = an[r] + bns;
        }
    }
}

// ---------------------------------------------------------------------------
// Note-LSTM recurrence on precomputed pre-activations.
// One thread per (b,t) sequence.  Gate order g: 0,1=i 2,3=f 4,5=g 6,7=o.
// ---------------------------------------------------------------------------
__global__ __launch_bounds__(64) void note_out_kernel(
    const float* __restrict__ Gn,    // [SEQ2_][NOTES][8] f32
    const float* __restrict__ Whh,   // [8][2] f32
    float* __restrict__ out)         // [B][T][156] f32
{
    const int q = blockIdx.x * 64 + threadIdx.x;
    if (q >= SEQ2_) return;

    float w0[8], w1[8];
    #pragma unroll
    for (int g = 0; g < 8; ++g) { w0[g] = Whh[g * 2]; w1[g] = Whh[g * 2 + 1]; }

    const float* gp = Gn + (size_t)q * (NOTES_ * 8);
    float* op = out + (size_t)q * (NOTES_ * 2);

    float h0 = 0.f, h1 = 0.f, c0 = 0.f, c1 = 0.f;
    f32x4 ga = *(const f32x4*)(gp);
    f32x4 gb = *(const f32x4*)(gp + 4);
    for (int n = 0; n < NOTES_; ++n) {
        f32x4 na, nb;
        if (n + 1 < NOTES_) {
            na = *(const f32x4*)(gp + (n + 1) * 8);
            nb = *(const f32x4*)(gp + (n + 1) * 8 + 4);
        }
        const float i0 = ga[0] + w0[0] * h0 + w1[0] * h1;
        const float i1 = ga[1] + w0[1] * h0 + w1[1] * h1;
        const float f0 = ga[2] + w0[2] * h0 + w1[2] * h1;
        const float f1 = ga[3] + w0[3] * h0 + w1[3] * h1;
        const float g0 = gb[0] + w0[4] * h0 + w1[4] * h1;
        const float g1 = gb[1] + w0[5] * h0 + w1[5] * h1;
        const float o0 = gb[2] + w0[6] * h0 + w1[6] * h1;
        const float o1 = gb[3] + w0[7] * h0 + w1[7] * h1;
        c0 = sigm(f0) * c0 + sigm(i0) * tanh_(g0);
        c1 = sigm(f1) * c1 + sigm(i1) * tanh_(g1);
        h0 = sigm(o0) * tanh_(c0);
        h1 = sigm(o1) * tanh_(c1);
        op[n * 2 + 0] = h0;
        op[n * 2 + 1] = h1;
        ga = na; gb = nb;
    }
}

extern "C" void kernel_launch(void* const* d_in, const int* in_sizes, int n_in,
                              void* d_out, int out_size, void* d_ws, size_t ws_size,
                              hipStream_t stream) {
    const float* x     = (const float*)d_in[0];
    const float* Wih_t = (const float*)d_in[1];
    const float* Whh_t = (const float*)d_in[2];
    const float* bih_t = (const float*)d_in[3];
    const float* bhh_t = (const float*)d_in[4];
    const float* Wih_n = (const float*)d_in[5];
    const float* Whh_n = (const float*)d_in[6];
    const float* bih_n = (const float*)d_in[7];
    const float* bhh_n = (const float*)d_in[8];
    float* out = (float*)d_out;

    // Workspace: Gn only (10.2 MB)
    float* Gn = (float*)d_ws;
    time_lstm_kernel<<<NBLK1, 512, 0, stream>>>(
        x, Wih_t, Whh_t, bih_t, bhh_t, Wih_n, bih_n, bhh_n, Gn);
    note_out_kernel<<<SEQ2_ / 64, 64, 0, stream>>>(Gn, Whh_n, out);
}

// Round 4
// 378.392 us; speedup vs baseline: 1.3201x; 1.3201x over previous
//
#include <hip/hip_runtime.h>

// Problem constants
#define B_     32
#define NOTES_ 78
#define T_     128
#define IN_    80
#define H_     128
#define NSEQ_  (B_*NOTES_)    // 2496
#define MBLK   16             // sequences per block (A-tile rows of 16x16x32 MFMA)
#define NBLK1  (NSEQ_/MBLK)   // 156 blocks (hard cap: recurrence keeps a 16-seq tile per block)
#define SEQ2_  (B_*T_)        // 4096 note-LSTM sequences
#define XN8    (NSEQ_*T_*IN_/8)
#define SHSTR  136            // sH row stride in shorts (272 B, 16B-aligned for b128)

typedef __attribute__((ext_vector_type(8))) short short8;   // 8 x bf16 (4 VGPRs)
typedef __attribute__((ext_vector_type(4))) float f32x4;

__device__ __forceinline__ unsigned short f2bf(float f) {
    unsigned u; __builtin_memcpy(&u, &f, 4);
    u += 0x7fffu + ((u >> 16) & 1u);          // RNE
    return (unsigned short)(u >> 16);
}
__device__ __forceinline__ short8 pack8(const float* p) {   // init-time only
    short8 r;
    #pragma unroll
    for (int k = 0; k < 8; ++k) r[k] = (short)f2bf(p[k]);
    return r;
}
// v_rcp_f32 instead of the full-precision divide sequence: ~1ulp, far inside
// the bf16-dominated error budget.
__device__ __forceinline__ float rcpf(float x)  { return __builtin_amdgcn_rcpf(x); }
__device__ __forceinline__ float sigm(float x)  { return rcpf(1.f + __expf(-x)); }
__device__ __forceinline__ float tanh_(float x) { return 2.f * rcpf(1.f + __expf(-2.f*x)) - 1.f; }

// ---------------------------------------------------------------------------
// Phase A: convert x f32 -> bf16 (memory-bound, ~153 MB traffic, ~30 us).
// Restored from round 2: keeping the conversion OUT of the recurrence loop
// keeps the loop's transient register pressure minimal (bf16 loads land
// directly in the 12 ax VGPRs; the f32->bf16-in-loop variant kept ~48 f32
// staging regs live and amplified spilling).
// ---------------------------------------------------------------------------
__global__ __launch_bounds__(256) void xcvt_kernel(
    const float* __restrict__ x, unsigned short* __restrict__ xb)
{
    const int i = blockIdx.x * 256 + threadIdx.x;
    if (i < XN8) {
        const f32x4 a = *(const f32x4*)(x + (size_t)i * 8);
        const f32x4 b = *(const f32x4*)(x + (size_t)i * 8 + 4);
        short8 r;
        #pragma unroll
        for (int k = 0; k < 4; ++k) { r[k] = (short)f2bf(a[k]); r[4+k] = (short)f2bf(b[k]); }
        *(short8*)(xb + (size_t)i * 8) = r;
    }
}

// ---------------------------------------------------------------------------
// Fused time LSTM + note-gate pre-activations.  8 waves / 512 thr / block;
// 16 sequences per block; 156 blocks (grid capped by the recurrence =>
// latency-bound: total time = 128 x step critical path).
//
// THIS ROUND: amdgpu_waves_per_eu(1, 2).  launch_bounds(512, {1,2}) only sets
// the MIN waves/EU; the backend still targeted 4 waves/EU (128-VGPR budget)
// and spilled the ~200-reg live set (weights wf/hf/wn alone = 128 VGPRs),
// reloading weight fragments from scratch every step.  With <=1 block/CU
// (156 blocks, 256 CUs) the physical occupancy is 2 waves/EU no matter what,
// so capping the allocator's occupancy target at 2 unlocks the 256-reg
// budget at zero occupancy cost and removes every per-step spill reload.
//
// Step pipeline (unchanged from round 2):
//   - accX[g] = bias + x(t+1).Wih^T computed during step t (off critical path)
//   - step t's gates start from C-input accX -> h-dependent chain is 4 MFMAs
//   - x(t+2) prefetched with a full-step window
//   - Gn duty (note-LSTM pre-activations from h(t-1)) rotates across waves
//   - ONE raw s_barrier per step, lgkmcnt(0) only (global traffic never
//     drains at the barrier); sH double-buffered so one barrier is race-free
// ---------------------------------------------------------------------------
template<bool XB16>
__global__ __launch_bounds__(512)
__attribute__((amdgpu_waves_per_eu(1, 2)))
void time_lstm_kernel(
    const void* __restrict__ xin,    // [NSEQ][T][IN] bf16 (XB16) or f32
    const float* __restrict__ Wih,   // [512][80]  f32
    const float* __restrict__ Whh,   // [512][128] f32
    const float* __restrict__ bih,   // [512] f32
    const float* __restrict__ bhh,   // [512] f32
    const float* __restrict__ Wn,    // [8][128] f32 (Wih_n)
    const float* __restrict__ bn1,   // [8] f32
    const float* __restrict__ bn2,   // [8] f32
    float* __restrict__ Gn)          // [B*T][NOTES][8] f32 (ws)
{
    __shared__ unsigned short sH[2][MBLK * SHSTR];   // 8.7 KB total

    const int tid  = threadIdx.x;
    const int wave = tid >> 6, lane = tid & 63;
    const int m16  = lane & 15, quad = lane >> 4;
    const int seq0 = blockIdx.x * MBLK;
    const int j    = wave * 16 + m16;          // this lane's h-column

    for (int i = tid; i < 2 * MBLK * SHSTR; i += 512)
        ((unsigned short*)sH)[i] = 0;          // h(-1) = 0

    // ---- weight B-fragments (f32 -> bf16): 4 gates x (3 Wih + 4 Whh) ----
    const short8 zero8 = (short8){0,0,0,0,0,0,0,0};
    short8 wf[4][3], hf[4][4];
    #pragma unroll
    for (int g = 0; g < 4; ++g) {
        const int n = g * H_ + j;              // gate column in [0,512)
        #pragma unroll
        for (int kt = 0; kt < 3; ++kt) {
            const int k = kt * 32 + quad * 8;
            wf[g][kt] = (k < IN_) ? pack8(Wih + n * IN_ + k) : zero8;
        }
        #pragma unroll
        for (int kt = 0; kt < 4; ++kt)
            hf[g][kt] = pack8(Whh + n * H_ + kt * 32 + quad * 8);
    }

    // ---- note-gate fragments + output addressing (ALL waves: Gn rotates) ----
    short8 wn[4];
    #pragma unroll
    for (int kt = 0; kt < 4; ++kt)
        wn[kt] = (m16 < 8) ? pack8(Wn + m16 * H_ + kt * 32 + quad * 8) : zero8;
    const float bns = (m16 < 8) ? (bn1[m16] + bn2[m16]) : 0.f;
    unsigned gbase[4];
    #pragma unroll
    for (int r = 0; r < 4; ++r) {
        const int sq = seq0 + quad * 4 + r;
        const int bb = sq / NOTES_;
        const int nn = sq - bb * NOTES_;
        gbase[r] = ((unsigned)bb * (T_ * NOTES_) + (unsigned)nn) * 8u + (unsigned)m16;
    }

    // ---- per-lane biases for column j (folded into accX init below) ----
    float bg4[4];
    #pragma unroll
    for (int g = 0; g < 4; ++g) bg4[g] = bih[g * H_ + j] + bhh[g * H_ + j];

    // ---- x A-fragment pointers (lane m16 -> sequence row) ----
    const float* xrf = XB16 ? nullptr
        : ((const float*)xin + (size_t)(seq0 + m16) * T_ * IN_);
    const unsigned short* xrb = XB16
        ? ((const unsigned short*)xin + (size_t)(seq0 + m16) * T_ * IN_) : nullptr;

    short8 ax0, ax1, ax2 = zero8;
    // load x(0)
    if (XB16) {
        const unsigned short* p = xrb;
        ax0 = *(const short8*)(p + quad * 8);
        ax1 = *(const short8*)(p + 32 + quad * 8);
        if (quad < 2) ax2 = *(const short8*)(p + 64 + quad * 8);
    } else {
        const float* p = xrf;
        ax0 = pack8(p + quad * 8);
        ax1 = pack8(p + 32 + quad * 8);
        if (quad < 2) ax2 = pack8(p + 64 + quad * 8);
    }

    // prologue: accX(0) = bias + x(0).Wih^T
    f32x4 accX[4];
    #pragma unroll
    for (int g = 0; g < 4; ++g) {
        accX[g] = (f32x4){bg4[g], bg4[g], bg4[g], bg4[g]};
        accX[g] = __builtin_amdgcn_mfma_f32_16x16x32_bf16(ax0, wf[g][0], accX[g], 0, 0, 0);
        accX[g] = __builtin_amdgcn_mfma_f32_16x16x32_bf16(ax1, wf[g][1], accX[g], 0, 0, 0);
        accX[g] = __builtin_amdgcn_mfma_f32_16x16x32_bf16(ax2, wf[g][2], accX[g], 0, 0, 0);
    }
    // load x(1)
    if (XB16) {
        const unsigned short* p = xrb + IN_;
        ax0 = *(const short8*)(p + quad * 8);
        ax1 = *(const short8*)(p + 32 + quad * 8);
        if (quad < 2) ax2 = *(const short8*)(p + 64 + quad * 8);
    } else {
        const float* p = xrf + IN_;
        ax0 = pack8(p + quad * 8);
        ax1 = pack8(p + 32 + quad * 8);
        if (quad < 2) ax2 = pack8(p + 64 + quad * 8);
    }

    float cst[4] = {0.f, 0.f, 0.f, 0.f};       // cell state, in-register

    __syncthreads();                            // init fence (once; full drain ok)

    for (int t = 0; t < T_; ++t) {
        const unsigned short* sHr = sH[t & 1];          // holds h(t-1)
        unsigned short*       sHw = sH[(t & 1) ^ 1];    // receives h(t)

        // h(t-1) A-fragments (identical across waves)
        short8 ah[4];
        #pragma unroll
        for (int kt = 0; kt < 4; ++kt)
            ah[kt] = *(const short8*)(sHr + m16 * SHSTR + kt * 32 + quad * 8);

        // main gate MFMAs: start from accX (bias + x-part), 4-deep h chain
        f32x4 acc[4];
        #pragma unroll
        for (int g = 0; g < 4; ++g) {
            acc[g] = accX[g];
            #pragma unroll
            for (int kt = 0; kt < 4; ++kt)
                acc[g] = __builtin_amdgcn_mfma_f32_16x16x32_bf16(ah[kt], hf[g][kt], acc[g], 0, 0, 0);
        }

        // note-gate tile for step t-1 (rotating wave; uses same ah)
        if (t > 0 && wave == ((t - 1) & 7)) {
            f32x4 an = (f32x4){0.f, 0.f, 0.f, 0.f};
            #pragma unroll
            for (int kt = 0; kt < 4; ++kt)
                an = __builtin_amdgcn_mfma_f32_16x16x32_bf16(ah[kt], wn[kt], an, 0, 0, 0);
            if (m16 < 8) {
                #pragma unroll
                for (int r = 0; r < 4; ++r)
                    Gn[gbase[r] + (unsigned)(t - 1) * (NOTES_ * 8)] = an[r] + bns;
            }
        }

        // accX(t+1) = bias + x(t+1).Wih^T  -- off critical path (no h dep)
        if (t + 1 < T_) {
            #pragma unroll
            for (int g = 0; g < 4; ++g) {
                accX[g] = (f32x4){bg4[g], bg4[g], bg4[g], bg4[g]};
                accX[g] = __builtin_amdgcn_mfma_f32_16x16x32_bf16(ax0, wf[g][0], accX[g], 0, 0, 0);
                accX[g] = __builtin_amdgcn_mfma_f32_16x16x32_bf16(ax1, wf[g][1], accX[g], 0, 0, 0);
                accX[g] = __builtin_amdgcn_mfma_f32_16x16x32_bf16(ax2, wf[g][2], accX[g], 0, 0, 0);
            }
        }

        // prefetch x(t+2): consumed next step by the accX MFMAs (full-step
        // window); never drained at the barrier (lgkmcnt-only wait below)
        if (t + 2 < T_) {
            if (XB16) {
                const unsigned short* p = xrb + (t + 2) * IN_;
                ax0 = *(const short8*)(p + quad * 8);
                ax1 = *(const short8*)(p + 32 + quad * 8);
                if (quad < 2) ax2 = *(const short8*)(p + 64 + quad * 8);
            } else {
                const float* p = xrf + (t + 2) * IN_;
                ax0 = pack8(p + quad * 8);
                ax1 = pack8(p + 32 + quad * 8);
                if (quad < 2) ax2 = pack8(p + 64 + quad * 8);
            }
        }

        // in-register LSTM cell update: lane holds i,f,g,o for 4 seqs at col j
        // (biases already inside acc via accX init)
        #pragma unroll
        for (int r = 0; r < 4; ++r) {
            const float cf = sigm(acc[1][r]) * cst[r] + sigm(acc[0][r]) * tanh_(acc[2][r]);
            cst[r] = cf;
            const float h = sigm(acc[3][r]) * tanh_(cf);
            sHw[(quad * 4 + r) * SHSTR + j] = f2bf(h);
        }

        // ONE barrier per step; double-buffered sH makes it race-free.
        // sched_barrier pins ds ops around the asm waitcnt (guide rule #18).
        __builtin_amdgcn_sched_barrier(0);
        asm volatile("s_waitcnt lgkmcnt(0)" ::: "memory");
        __builtin_amdgcn_s_barrier();
        __builtin_amdgcn_sched_barrier(0);
    }

    // epilogue: note-gate tile for t = T-1 (h(127) sits in sH[0])
    if (wave == ((T_ - 1) & 7)) {
        const unsigned short* sHr = sH[T_ & 1];
        short8 ah[4];
        #pragma unroll
        for (int kt = 0; kt < 4; ++kt)
            ah[kt] = *(const short8*)(sHr + m16 * SHSTR + kt * 32 + quad * 8);
        f32x4 an = (f32x4){0.f, 0.f, 0.f, 0.f};
        #pragma unroll
        for (int kt = 0; kt < 4; ++kt)
            an = __builtin_amdgcn_mfma_f32_16x16x32_bf16(ah[kt], wn[kt], an, 0, 0, 0);
        if (m16 < 8) {
            #pragma unroll
            for (int r = 0; r < 4; ++r)
                Gn[gbase[r] + (unsigned)(T_ - 1) * (NOTES_ * 8)] = an[r] + bns;
        }
    }
}

// ---------------------------------------------------------------------------
// Note-LSTM recurrence on precomputed pre-activations.
// One thread per (b,t) sequence.  Gate order g: 0,1=i 2,3=f 4,5=g 6,7=o.
// ---------------------------------------------------------------------------
__global__ __launch_bounds__(64) void note_out_kernel(
    const float* __restrict__ Gn,    // [SEQ2_][NOTES][8] f32
    const float* __restrict__ Whh,   // [8][2] f32
    float* __restrict__ out)         // [B][T][156] f32
{
    const int q = blockIdx.x * 64 + threadIdx.x;
    if (q >= SEQ2_) return;

    float w0[8], w1[8];
    #pragma unroll
    for (int g = 0; g < 8; ++g) { w0[g] = Whh[g * 2]; w1[g] = Whh[g * 2 + 1]; }

    const float* gp = Gn + (size_t)q * (NOTES_ * 8);
    float* op = out + (size_t)q * (NOTES_ * 2);

    float h0 = 0.f, h1 = 0.f, c0 = 0.f, c1 = 0.f;
    f32x4 ga = *(const f32x4*)(gp);
    f32x4 gb = *(const f32x4*)(gp + 4);
    for (int n = 0; n < NOTES_; ++n) {
        f32x4 na, nb;
        if (n + 1 < NOTES_) {
            na = *(const f32x4*)(gp + (n + 1) * 8);
            nb = *(const f32x4*)(gp + (n + 1) * 8 + 4);
        }
        const float i0 = ga[0] + w0[0] * h0 + w1[0] * h1;
        const float i1 = ga[1] + w0[1] * h0 + w1[1] * h1;
        const float f0 = ga[2] + w0[2] * h0 + w1[2] * h1;
        const float f1 = ga[3] + w0[3] * h0 + w1[3] * h1;
        const float g0 = gb[0] + w0[4] * h0 + w1[4] * h1;
        const float g1 = gb[1] + w0[5] * h0 + w1[5] * h1;
        const float o0 = gb[2] + w0[6] * h0 + w1[6] * h1;
        const float o1 = gb[3] + w0[7] * h0 + w1[7] * h1;
        c0 = sigm(f0) * c0 + sigm(i0) * tanh_(g0);
        c1 = sigm(f1) * c1 + sigm(i1) * tanh_(g1);
        h0 = sigm(o0) * tanh_(c0);
        h1 = sigm(o1) * tanh_(c1);
        op[n * 2 + 0] = h0;
        op[n * 2 + 1] = h1;
        ga = na; gb = nb;
    }
}

extern "C" void kernel_launch(void* const* d_in, const int* in_sizes, int n_in,
                              void* d_out, int out_size, void* d_ws, size_t ws_size,
                              hipStream_t stream) {
    const float* x     = (const float*)d_in[0];
    const float* Wih_t = (const float*)d_in[1];
    const float* Whh_t = (const float*)d_in[2];
    const float* bih_t = (const float*)d_in[3];
    const float* bhh_t = (const float*)d_in[4];
    const float* Wih_n = (const float*)d_in[5];
    const float* Whh_n = (const float*)d_in[6];
    const float* bih_n = (const float*)d_in[7];
    const float* bhh_n = (const float*)d_in[8];
    float* out = (float*)d_out;

    const size_t xb_bytes = (size_t)NSEQ_ * T_ * IN_ * 2;          // 51.1 MB
    const size_t gn_bytes = (size_t)SEQ2_ * NOTES_ * 8 * 4;        // 10.2 MB

    if (ws_size >= xb_bytes + gn_bytes) {
        // Layout: [xb16 51.1MB][Gn 10.2MB]
        unsigned short* xb = (unsigned short*)d_ws;
        float* Gn = (float*)((char*)d_ws + xb_bytes);
        xcvt_kernel<<<(XN8 + 255) / 256, 256, 0, stream>>>(x, xb);
        time_lstm_kernel<true><<<NBLK1, 512, 0, stream>>>(
            xb, Wih_t, Whh_t, bih_t, bhh_t, Wih_n, bih_n, bhh_n, Gn);
        note_out_kernel<<<SEQ2_ / 64, 64, 0, stream>>>(Gn, Whh_n, out);
    } else {
        // Fallback: no x pre-convert; Gn at ws base.
        float* Gn = (float*)d_ws;
        time_lstm_kernel<false><<<NBLK1, 512, 0, stream>>>(
            x, Wih_t, Whh_t, bih_t, bhh_t, Wih_n, bih_n, bhh_n, Gn);
        note_out_kernel<<<SEQ2_ / 64, 64, 0, stream>>>(Gn, Whh_n, out);
    }
}

// Round 5
// 358.105 us; speedup vs baseline: 1.3949x; 1.0566x over previous
//
#include <hip/hip_runtime.h>

// Problem constants
#define B_     32
#define NOTES_ 78
#define T_     128
#define IN_    80
#define H_     128
#define NSEQ_  (B_*NOTES_)    // 2496
#define MBLK   16             // sequences per block (A-tile rows of 16x16x32 MFMA)
#define NBLK1  (NSEQ_/MBLK)   // 156 blocks (hard cap: recurrence keeps a 16-seq tile per block)
#define SEQ2_  (B_*T_)        // 4096 note-LSTM sequences
#define XN8    (NSEQ_*T_*IN_/8)
#define SHSTR  136            // sH row stride in shorts (272 B, 16B-aligned for b128)

typedef __attribute__((ext_vector_type(8))) short short8;   // 8 x bf16 (4 VGPRs)
typedef __attribute__((ext_vector_type(4))) float f32x4;

__device__ __forceinline__ unsigned short f2bf(float f) {
    unsigned u; __builtin_memcpy(&u, &f, 4);
    u += 0x7fffu + ((u >> 16) & 1u);          // RNE
    return (unsigned short)(u >> 16);
}
__device__ __forceinline__ short8 pack8(const float* p) {   // init-time only
    short8 r;
    #pragma unroll
    for (int k = 0; k < 8; ++k) r[k] = (short)f2bf(p[k]);
    return r;
}
// v_rcp_f32 instead of the full-precision divide sequence: ~1ulp, far inside
// the bf16-dominated error budget.
__device__ __forceinline__ float rcpf(float x)  { return __builtin_amdgcn_rcpf(x); }
__device__ __forceinline__ float sigm(float x)  { return rcpf(1.f + __expf(-x)); }
__device__ __forceinline__ float tanh_(float x) { return 2.f * rcpf(1.f + __expf(-2.f*x)) - 1.f; }

// ---------------------------------------------------------------------------
// Phase A: convert x f32 -> bf16 (memory-bound, ~153 MB traffic, ~30 us).
// Keeping the conversion OUT of the recurrence loop keeps the loop's
// transient register pressure minimal (round-3 lesson).
// ---------------------------------------------------------------------------
__global__ __launch_bounds__(256) void xcvt_kernel(
    const float* __restrict__ x, unsigned short* __restrict__ xb)
{
    const int i = blockIdx.x * 256 + threadIdx.x;
    if (i < XN8) {
        const f32x4 a = *(const f32x4*)(x + (size_t)i * 8);
        const f32x4 b = *(const f32x4*)(x + (size_t)i * 8 + 4);
        short8 r;
        #pragma unroll
        for (int k = 0; k < 4; ++k) { r[k] = (short)f2bf(a[k]); r[4+k] = (short)f2bf(b[k]); }
        *(short8*)(xb + (size_t)i * 8) = r;
    }
}

// ---------------------------------------------------------------------------
// Fused time LSTM + note-gate pre-activations.  8 waves / 512 thr / block;
// 16 sequences per block; 156 blocks; latency-bound (128 serial steps).
//
// THIS ROUND: phase-stagger of the two co-resident waves per SIMD.
// Waves map to SIMDs as w%4, so SIMD s hosts waves {s, s+4}.  The barrier
// forces both into lockstep; with identical phase order their VALU phases
// collide and their matrix phases collide (pipes sum instead of overlap:
// measured VALU 1530 + MFMA 915 + idle 1200 cyc/step on active SIMDs).
// Group A (w<4):  hMFMA -> cell/ds_write -> Gn -> accX/prefetch
// Group B (w>=4): hMFMA -> accX/prefetch -> cell/ds_write -> Gn
// => A's cell-VALU overlaps B's accX-MFMA and vice versa.
// ds_read(ah) hoisted to step top (LDS latency starts before compute);
// Gn moved after ds_write (shortens barrier->h-in-LDS chain).
// accX single-buffered: consumed by acc-init before recompute in both orders.
// ---------------------------------------------------------------------------
#define ACCX_AND_PREFETCH                                                              \
    if (t + 1 < T_) {                                                                  \
        _Pragma("unroll")                                                              \
        for (int g = 0; g < 4; ++g) {                                                  \
            accX[g] = (f32x4){bg4[g], bg4[g], bg4[g], bg4[g]};                         \
            accX[g] = __builtin_amdgcn_mfma_f32_16x16x32_bf16(ax0, wf[g][0], accX[g], 0, 0, 0); \
            accX[g] = __builtin_amdgcn_mfma_f32_16x16x32_bf16(ax1, wf[g][1], accX[g], 0, 0, 0); \
            accX[g] = __builtin_amdgcn_mfma_f32_16x16x32_bf16(ax2, wf[g][2], accX[g], 0, 0, 0); \
        }                                                                              \
    }                                                                                  \
    if (t + 2 < T_) {                                                                  \
        if (XB16) {                                                                    \
            const unsigned short* p = xrb + (t + 2) * IN_;                             \
            ax0 = *(const short8*)(p + quad * 8);                                      \
            ax1 = *(const short8*)(p + 32 + quad * 8);                                 \
            if (quad < 2) ax2 = *(const short8*)(p + 64 + quad * 8);                   \
        } else {                                                                       \
            const float* p = xrf + (t + 2) * IN_;                                      \
            ax0 = pack8(p + quad * 8);                                                 \
            ax1 = pack8(p + 32 + quad * 8);                                            \
            if (quad < 2) ax2 = pack8(p + 64 + quad * 8);                              \
        }                                                                              \
    }

#define CELL_AND_H_WRITE                                                               \
    _Pragma("unroll")                                                                  \
    for (int r = 0; r < 4; ++r) {                                                      \
        const float cf = sigm(acc[1][r]) * cst[r] + sigm(acc[0][r]) * tanh_(acc[2][r]);\
        cst[r] = cf;                                                                   \
        const float h = sigm(acc[3][r]) * tanh_(cf);                                   \
        sHw[(quad * 4 + r) * SHSTR + j] = f2bf(h);                                     \
    }

#define GN_TILE                                                                        \
    if (t > 0 && wave == ((t - 1) & 7)) {                                              \
        f32x4 an = (f32x4){0.f, 0.f, 0.f, 0.f};                                        \
        _Pragma("unroll")                                                              \
        for (int kt = 0; kt < 4; ++kt)                                                 \
            an = __builtin_amdgcn_mfma_f32_16x16x32_bf16(ah[kt], wn[kt], an, 0, 0, 0); \
        if (m16 < 8) {                                                                 \
            _Pragma("unroll")                                                          \
            for (int r = 0; r < 4; ++r)                                                \
                Gn[gbase[r] + (unsigned)(t - 1) * (NOTES_ * 8)] = an[r] + bns;         \
        }                                                                              \
    }

template<bool XB16>
__global__ __launch_bounds__(512)
__attribute__((amdgpu_waves_per_eu(1, 2)))
void time_lstm_kernel(
    const void* __restrict__ xin,    // [NSEQ][T][IN] bf16 (XB16) or f32
    const float* __restrict__ Wih,   // [512][80]  f32
    const float* __restrict__ Whh,   // [512][128] f32
    const float* __restrict__ bih,   // [512] f32
    const float* __restrict__ bhh,   // [512] f32
    const float* __restrict__ Wn,    // [8][128] f32 (Wih_n)
    const float* __restrict__ bn1,   // [8] f32
    const float* __restrict__ bn2,   // [8] f32
    float* __restrict__ Gn)          // [B*T][NOTES][8] f32 (ws)
{
    __shared__ unsigned short sH[2][MBLK * SHSTR];   // 8.7 KB total

    const int tid  = threadIdx.x;
    const int wave = tid >> 6, lane = tid & 63;
    const int m16  = lane & 15, quad = lane >> 4;
    const int seq0 = blockIdx.x * MBLK;
    const int j    = wave * 16 + m16;          // this lane's h-column
    const bool grpB = (wave >= 4);             // SIMD s hosts waves {s, s+4}

    for (int i = tid; i < 2 * MBLK * SHSTR; i += 512)
        ((unsigned short*)sH)[i] = 0;          // h(-1) = 0

    // ---- weight B-fragments (f32 -> bf16): 4 gates x (3 Wih + 4 Whh) ----
    const short8 zero8 = (short8){0,0,0,0,0,0,0,0};
    short8 wf[4][3], hf[4][4];
    #pragma unroll
    for (int g = 0; g < 4; ++g) {
        const int n = g * H_ + j;              // gate column in [0,512)
        #pragma unroll
        for (int kt = 0; kt < 3; ++kt) {
            const int k = kt * 32 + quad * 8;
            wf[g][kt] = (k < IN_) ? pack8(Wih + n * IN_ + k) : zero8;
        }
        #pragma unroll
        for (int kt = 0; kt < 4; ++kt)
            hf[g][kt] = pack8(Whh + n * H_ + kt * 32 + quad * 8);
    }

    // ---- note-gate fragments + output addressing (ALL waves: Gn rotates) ----
    short8 wn[4];
    #pragma unroll
    for (int kt = 0; kt < 4; ++kt)
        wn[kt] = (m16 < 8) ? pack8(Wn + m16 * H_ + kt * 32 + quad * 8) : zero8;
    const float bns = (m16 < 8) ? (bn1[m16] + bn2[m16]) : 0.f;
    unsigned gbase[4];
    #pragma unroll
    for (int r = 0; r < 4; ++r) {
        const int sq = seq0 + quad * 4 + r;
        const int bb = sq / NOTES_;
        const int nn = sq - bb * NOTES_;
        gbase[r] = ((unsigned)bb * (T_ * NOTES_) + (unsigned)nn) * 8u + (unsigned)m16;
    }

    // ---- per-lane biases for column j (folded into accX init) ----
    float bg4[4];
    #pragma unroll
    for (int g = 0; g < 4; ++g) bg4[g] = bih[g * H_ + j] + bhh[g * H_ + j];

    // ---- x A-fragment pointers (lane m16 -> sequence row) ----
    const float* xrf = XB16 ? nullptr
        : ((const float*)xin + (size_t)(seq0 + m16) * T_ * IN_);
    const unsigned short* xrb = XB16
        ? ((const unsigned short*)xin + (size_t)(seq0 + m16) * T_ * IN_) : nullptr;

    short8 ax0, ax1, ax2 = zero8;
    // load x(0)
    if (XB16) {
        const unsigned short* p = xrb;
        ax0 = *(const short8*)(p + quad * 8);
        ax1 = *(const short8*)(p + 32 + quad * 8);
        if (quad < 2) ax2 = *(const short8*)(p + 64 + quad * 8);
    } else {
        const float* p = xrf;
        ax0 = pack8(p + quad * 8);
        ax1 = pack8(p + 32 + quad * 8);
        if (quad < 2) ax2 = pack8(p + 64 + quad * 8);
    }

    // prologue: accX(0) = bias + x(0).Wih^T
    f32x4 accX[4];
    #pragma unroll
    for (int g = 0; g < 4; ++g) {
        accX[g] = (f32x4){bg4[g], bg4[g], bg4[g], bg4[g]};
        accX[g] = __builtin_amdgcn_mfma_f32_16x16x32_bf16(ax0, wf[g][0], accX[g], 0, 0, 0);
        accX[g] = __builtin_amdgcn_mfma_f32_16x16x32_bf16(ax1, wf[g][1], accX[g], 0, 0, 0);
        accX[g] = __builtin_amdgcn_mfma_f32_16x16x32_bf16(ax2, wf[g][2], accX[g], 0, 0, 0);
    }
    // load x(1)
    if (XB16) {
        const unsigned short* p = xrb + IN_;
        ax0 = *(const short8*)(p + quad * 8);
        ax1 = *(const short8*)(p + 32 + quad * 8);
        if (quad < 2) ax2 = *(const short8*)(p + 64 + quad * 8);
    } else {
        const float* p = xrf + IN_;
        ax0 = pack8(p + quad * 8);
        ax1 = pack8(p + 32 + quad * 8);
        if (quad < 2) ax2 = pack8(p + 64 + quad * 8);
    }

    float cst[4] = {0.f, 0.f, 0.f, 0.f};       // cell state, in-register

    __syncthreads();                            // init fence (once; full drain ok)

    for (int t = 0; t < T_; ++t) {
        const unsigned short* sHr = sH[t & 1];          // holds h(t-1)
        unsigned short*       sHw = sH[(t & 1) ^ 1];    // receives h(t)

        // h(t-1) A-fragments first: LDS latency starts before any compute
        short8 ah[4];
        #pragma unroll
        for (int kt = 0; kt < 4; ++kt)
            ah[kt] = *(const short8*)(sHr + m16 * SHSTR + kt * 32 + quad * 8);

        // main gate MFMAs: start from accX (bias + x-part), 4-deep h chain
        f32x4 acc[4];
        #pragma unroll
        for (int g = 0; g < 4; ++g) {
            acc[g] = accX[g];
            #pragma unroll
            for (int kt = 0; kt < 4; ++kt)
                acc[g] = __builtin_amdgcn_mfma_f32_16x16x32_bf16(ah[kt], hf[g][kt], acc[g], 0, 0, 0);
        }

        if (grpB) {
            // B order: matrix filler first, then VALU
            ACCX_AND_PREFETCH
            CELL_AND_H_WRITE
            GN_TILE
        } else {
            // A order: VALU first, matrix filler last
            CELL_AND_H_WRITE
            GN_TILE
            ACCX_AND_PREFETCH
        }

        // ONE barrier per step; double-buffered sH makes it race-free.
        // sched_barrier pins ds ops around the asm waitcnt (guide rule #18).
        __builtin_amdgcn_sched_barrier(0);
        asm volatile("s_waitcnt lgkmcnt(0)" ::: "memory");
        __builtin_amdgcn_s_barrier();
        __builtin_amdgcn_sched_barrier(0);
    }

    // epilogue: note-gate tile for t = T-1 (h(127) sits in sH[0])
    if (wave == ((T_ - 1) & 7)) {
        const unsigned short* sHr = sH[T_ & 1];
        short8 ah[4];
        #pragma unroll
        for (int kt = 0; kt < 4; ++kt)
            ah[kt] = *(const short8*)(sHr + m16 * SHSTR + kt * 32 + quad * 8);
        f32x4 an = (f32x4){0.f, 0.f, 0.f, 0.f};
        #pragma unroll
        for (int kt = 0; kt < 4; ++kt)
            an = __builtin_amdgcn_mfma_f32_16x16x32_bf16(ah[kt], wn[kt], an, 0, 0, 0);
        if (m16 < 8) {
            #pragma unroll
            for (int r = 0; r < 4; ++r)
                Gn[gbase[r] + (unsigned)(T_ - 1) * (NOTES_ * 8)] = an[r] + bns;
        }
    }
}

// ---------------------------------------------------------------------------
// Note-LSTM recurrence on precomputed pre-activations.
// One thread per (b,t) sequence.  Gate order g: 0,1=i 2,3=f 4,5=g 6,7=o.
// ---------------------------------------------------------------------------
__global__ __launch_bounds__(64) void note_out_kernel(
    const float* __restrict__ Gn,    // [SEQ2_][NOTES][8] f32
    const float* __restrict__ Whh,   // [8][2] f32
    float* __restrict__ out)         // [B][T][156] f32
{
    const int q = blockIdx.x * 64 + threadIdx.x;
    if (q >= SEQ2_) return;

    float w0[8], w1[8];
    #pragma unroll
    for (int g = 0; g < 8; ++g) { w0[g] = Whh[g * 2]; w1[g] = Whh[g * 2 + 1]; }

    const float* gp = Gn + (size_t)q * (NOTES_ * 8);
    float* op = out + (size_t)q * (NOTES_ * 2);

    float h0 = 0.f, h1 = 0.f, c0 = 0.f, c1 = 0.f;
    f32x4 ga = *(const f32x4*)(gp);
    f32x4 gb = *(const f32x4*)(gp + 4);
    for (int n = 0; n < NOTES_; ++n) {
        f32x4 na, nb;
        if (n + 1 < NOTES_) {
            na = *(const f32x4*)(gp + (n + 1) * 8);
            nb = *(const f32x4*)(gp + (n + 1) * 8 + 4);
        }
        const float i0 = ga[0] + w0[0] * h0 + w1[0] * h1;
        const float i1 = ga[1] + w0[1] * h0 + w1[1] * h1;
        const float f0 = ga[2] + w0[2] * h0 + w1[2] * h1;
        const float f1 = ga[3] + w0[3] * h0 + w1[3] * h1;
        const float g0 = gb[0] + w0[4] * h0 + w1[4] * h1;
        const float g1 = gb[1] + w0[5] * h0 + w1[5] * h1;
        const float o0 = gb[2] + w0[6] * h0 + w1[6] * h1;
        const float o1 = gb[3] + w0[7] * h0 + w1[7] * h1;
        c0 = sigm(f0) * c0 + sigm(i0) * tanh_(g0);
        c1 = sigm(f1) * c1 + sigm(i1) * tanh_(g1);
        h0 = sigm(o0) * tanh_(c0);
        h1 = sigm(o1) * tanh_(c1);
        op[n * 2 + 0] = h0;
        op[n * 2 + 1] = h1;
        ga = na; gb = nb;
    }
}

extern "C" void kernel_launch(void* const* d_in, const int* in_sizes, int n_in,
                              void* d_out, int out_size, void* d_ws, size_t ws_size,
                              hipStream_t stream) {
    const float* x     = (const float*)d_in[0];
    const float* Wih_t = (const float*)d_in[1];
    const float* Whh_t = (const float*)d_in[2];
    const float* bih_t = (const float*)d_in[3];
    const float* bhh_t = (const float*)d_in[4];
    const float* Wih_n = (const float*)d_in[5];
    const float* Whh_n = (const float*)d_in[6];
    const float* bih_n = (const float*)d_in[7];
    const float* bhh_n = (const float*)d_in[8];
    float* out = (float*)d_out;

    const size_t xb_bytes = (size_t)NSEQ_ * T_ * IN_ * 2;          // 51.1 MB
    const size_t gn_bytes = (size_t)SEQ2_ * NOTES_ * 8 * 4;        // 10.2 MB

    if (ws_size >= xb_bytes + gn_bytes) {
        // Layout: [xb16 51.1MB][Gn 10.2MB]
        unsigned short* xb = (unsigned short*)d_ws;
        float* Gn = (float*)((char*)d_ws + xb_bytes);
        xcvt_kernel<<<(XN8 + 255) / 256, 256, 0, stream>>>(x, xb);
        time_lstm_kernel<true><<<NBLK1, 512, 0, stream>>>(
            xb, Wih_t, Whh_t, bih_t, bhh_t, Wih_n, bih_n, bhh_n, Gn);
        note_out_kernel<<<SEQ2_ / 64, 64, 0, stream>>>(Gn, Whh_n, out);
    } else {
        // Fallback: no x pre-convert; Gn at ws base.
        float* Gn = (float*)d_ws;
        time_lstm_kernel<false><<<NBLK1, 512, 0, stream>>>(
            x, Wih_t, Whh_t, bih_t, bhh_t, Wih_n, bih_n, bhh_n, Gn);
        note_out_kernel<<<SEQ2_ / 64, 64, 0, stream>>>(Gn, Whh_n, out);
    }
}

// Round 6
// 355.697 us; speedup vs baseline: 1.4044x; 1.0068x over previous
//
#include <hip/hip_runtime.h>

// Problem constants
#define B_     32
#define NOTES_ 78
#define T_     128
#define IN_    80
#define H_     128
#define NSEQ_  (B_*NOTES_)    // 2496
#define MBLK   16             // sequences per block (A-tile rows of 16x16x32 MFMA)
#define NBLK1  (NSEQ_/MBLK)   // 156 blocks (hard cap: recurrence keeps a 16-seq tile per block)
#define SEQ2_  (B_*T_)        // 4096 note-LSTM sequences
#define XN8    (NSEQ_*T_*IN_/8)
#define SHSTR  136            // sH row stride in shorts (272 B, 16B-aligned for b128)

typedef __attribute__((ext_vector_type(8))) short short8;   // 8 x bf16 (4 VGPRs)
typedef __attribute__((ext_vector_type(4))) float f32x4;

__device__ __forceinline__ unsigned short f2bf(float f) {
    unsigned u; __builtin_memcpy(&u, &f, 4);
    u += 0x7fffu + ((u >> 16) & 1u);          // RNE
    return (unsigned short)(u >> 16);
}
__device__ __forceinline__ short8 pack8(const float* p) {   // init-time only
    short8 r;
    #pragma unroll
    for (int k = 0; k < 8; ++k) r[k] = (short)f2bf(p[k]);
    return r;
}
// v_rcp_f32 instead of the full-precision divide sequence: ~1ulp, far inside
// the bf16-dominated error budget.
__device__ __forceinline__ float rcpf(float x)  { return __builtin_amdgcn_rcpf(x); }
__device__ __forceinline__ float sigm(float x)  { return rcpf(1.f + __expf(-x)); }
__device__ __forceinline__ float tanh_(float x) { return 2.f / (1.f + __expf(-2.f*x)) - 1.f; }
__device__ __forceinline__ float tanhr(float x) { return 2.f * rcpf(1.f + __expf(-2.f*x)) - 1.f; }

// ---------------------------------------------------------------------------
// Phase A: convert x f32 -> bf16 (memory-bound, ~153 MB traffic, ~27 us).
// ---------------------------------------------------------------------------
__global__ __launch_bounds__(256) void xcvt_kernel(
    const float* __restrict__ x, unsigned short* __restrict__ xb)
{
    const int i = blockIdx.x * 256 + threadIdx.x;
    if (i < XN8) {
        const f32x4 a = *(const f32x4*)(x + (size_t)i * 8);
        const f32x4 b = *(const f32x4*)(x + (size_t)i * 8 + 4);
        short8 r;
        #pragma unroll
        for (int k = 0; k < 4; ++k) { r[k] = (short)f2bf(a[k]); r[4+k] = (short)f2bf(b[k]); }
        *(short8*)(xb + (size_t)i * 8) = r;
    }
}

// ---------------------------------------------------------------------------
// Fused time LSTM + note-gate pre-activations.  8 waves / 512 thr / block;
// 16 sequences per block; 156 blocks; latency-bound (128 serial steps).
//
// THIS ROUND:
//  (1) combined-rcp cell update: e_i=e^{-i}, e_f=e^{-f}, e_g=e^{-2g},
//      e_o=e^{-o}; one rcp of (d_i d_f d_g d_o) reconstructs sigm(i), sigm(f),
//      sigm(o) and tanh(g)=2/d_g-1 -> 5 exp + 2 rcp per cell (was 5+5).
//      Exact rearrangement; overflow needs sum|gates| > ~88 (never at std~1.5).
//  (2) s_setprio(1) around MFMA clusters (T5): the group stagger gives the
//      SIMD a {matrix-phase, VALU-phase} wave pair -- the regime where
//      priority arbitration pays.
// Carried: per-SIMD phase stagger (waves {s, s+4}), accX pipelining, one raw
// s_barrier per step with lgkmcnt(0) only, double-buffered sH.
// ---------------------------------------------------------------------------
#define ACCX_AND_PREFETCH                                                              \
    if (t + 1 < T_) {                                                                  \
        __builtin_amdgcn_s_setprio(1);                                                 \
        _Pragma("unroll")                                                              \
        for (int g = 0; g < 4; ++g) {                                                  \
            accX[g] = (f32x4){bg4[g], bg4[g], bg4[g], bg4[g]};                         \
            accX[g] = __builtin_amdgcn_mfma_f32_16x16x32_bf16(ax0, wf[g][0], accX[g], 0, 0, 0); \
            accX[g] = __builtin_amdgcn_mfma_f32_16x16x32_bf16(ax1, wf[g][1], accX[g], 0, 0, 0); \
            accX[g] = __builtin_amdgcn_mfma_f32_16x16x32_bf16(ax2, wf[g][2], accX[g], 0, 0, 0); \
        }                                                                              \
        __builtin_amdgcn_s_setprio(0);                                                 \
    }                                                                                  \
    if (t + 2 < T_) {                                                                  \
        if (XB16) {                                                                    \
            const unsigned short* p = xrb + (t + 2) * IN_;                             \
            ax0 = *(const short8*)(p + quad * 8);                                      \
            ax1 = *(const short8*)(p + 32 + quad * 8);                                 \
            if (quad < 2) ax2 = *(const short8*)(p + 64 + quad * 8);                   \
        } else {                                                                       \
            const float* p = xrf + (t + 2) * IN_;                                      \
            ax0 = pack8(p + quad * 8);                                                 \
            ax1 = pack8(p + 32 + quad * 8);                                            \
            if (quad < 2) ax2 = pack8(p + 64 + quad * 8);                              \
        }                                                                              \
    }

// Cell update, combined-rcp form.  Identities (with d = 1+e):
//   sigm(i) = 1/d_i = R*d_f*d_g*d_o,  R = rcp(d_i*d_f*d_g*d_o)
//   tanh(g) = (1-e_g)/(1+e_g) = 2/d_g - 1,  e_g = e^{-2g}
// Batch the 4 cells' exps first (max trans ILP), then the reconstruction.
#define CELL_AND_H_WRITE                                                               \
    {                                                                                  \
        float ei[4], ef[4], eg[4], eo[4];                                              \
        _Pragma("unroll")                                                              \
        for (int r = 0; r < 4; ++r) {                                                  \
            ei[r] = __expf(-acc[0][r]);                                                \
            ef[r] = __expf(-acc[1][r]);                                                \
            eg[r] = __expf(-2.f * acc[2][r]);                                          \
            eo[r] = __expf(-acc[3][r]);                                                \
        }                                                                              \
        _Pragma("unroll")                                                              \
        for (int r = 0; r < 4; ++r) {                                                  \
            const float di = 1.f + ei[r], df = 1.f + ef[r];                            \
            const float dg = 1.f + eg[r], dd = 1.f + eo[r];                            \
            const float s1 = di * df, s2 = dg * dd;                                    \
            const float R  = rcpf(s1 * s2);                                            \
            const float Rs2 = R * s2, Rs1 = R * s1;                                    \
            const float si = Rs2 * df;              /* sigm(i) */                      \
            const float sf = Rs2 * di;              /* sigm(f) */                      \
            const float so = Rs1 * dg;              /* sigm(o) */                      \
            const float tg = 2.f * (Rs1 * dd) - 1.f;/* tanh(g) */                      \
            const float cf = sf * cst[r] + si * tg;                                    \
            cst[r] = cf;                                                               \
            const float h = so * tanhr(cf);                                            \
            sHw[(quad * 4 + r) * SHSTR + j] = f2bf(h);                                 \
        }                                                                              \
    }

#define GN_TILE                                                                        \
    if (t > 0 && wave == ((t - 1) & 7)) {                                              \
        f32x4 an = (f32x4){0.f, 0.f, 0.f, 0.f};                                        \
        __builtin_amdgcn_s_setprio(1);                                                 \
        _Pragma("unroll")                                                              \
        for (int kt = 0; kt < 4; ++kt)                                                 \
            an = __builtin_amdgcn_mfma_f32_16x16x32_bf16(ah[kt], wn[kt], an, 0, 0, 0); \
        __builtin_amdgcn_s_setprio(0);                                                 \
        if (m16 < 8) {                                                                 \
            _Pragma("unroll")                                                          \
            for (int r = 0; r < 4; ++r)                                                \
                Gn[gbase[r] + (unsigned)(t - 1) * (NOTES_ * 8)] = an[r] + bns;         \
        }                                                                              \
    }

template<bool XB16>
__global__ __launch_bounds__(512)
__attribute__((amdgpu_waves_per_eu(1, 2)))
void time_lstm_kernel(
    const void* __restrict__ xin,    // [NSEQ][T][IN] bf16 (XB16) or f32
    const float* __restrict__ Wih,   // [512][80]  f32
    const float* __restrict__ Whh,   // [512][128] f32
    const float* __restrict__ bih,   // [512] f32
    const float* __restrict__ bhh,   // [512] f32
    const float* __restrict__ Wn,    // [8][128] f32 (Wih_n)
    const float* __restrict__ bn1,   // [8] f32
    const float* __restrict__ bn2,   // [8] f32
    float* __restrict__ Gn)          // [B*T][NOTES][8] f32 (ws)
{
    __shared__ unsigned short sH[2][MBLK * SHSTR];   // 8.7 KB total

    const int tid  = threadIdx.x;
    const int wave = tid >> 6, lane = tid & 63;
    const int m16  = lane & 15, quad = lane >> 4;
    const int seq0 = blockIdx.x * MBLK;
    const int j    = wave * 16 + m16;          // this lane's h-column
    const bool grpB = (wave >= 4);             // SIMD s hosts waves {s, s+4}

    for (int i = tid; i < 2 * MBLK * SHSTR; i += 512)
        ((unsigned short*)sH)[i] = 0;          // h(-1) = 0

    // ---- weight B-fragments (f32 -> bf16): 4 gates x (3 Wih + 4 Whh) ----
    const short8 zero8 = (short8){0,0,0,0,0,0,0,0};
    short8 wf[4][3], hf[4][4];
    #pragma unroll
    for (int g = 0; g < 4; ++g) {
        const int n = g * H_ + j;              // gate column in [0,512)
        #pragma unroll
        for (int kt = 0; kt < 3; ++kt) {
            const int k = kt * 32 + quad * 8;
            wf[g][kt] = (k < IN_) ? pack8(Wih + n * IN_ + k) : zero8;
        }
        #pragma unroll
        for (int kt = 0; kt < 4; ++kt)
            hf[g][kt] = pack8(Whh + n * H_ + kt * 32 + quad * 8);
    }

    // ---- note-gate fragments + output addressing (ALL waves: Gn rotates) ----
    short8 wn[4];
    #pragma unroll
    for (int kt = 0; kt < 4; ++kt)
        wn[kt] = (m16 < 8) ? pack8(Wn + m16 * H_ + kt * 32 + quad * 8) : zero8;
    const float bns = (m16 < 8) ? (bn1[m16] + bn2[m16]) : 0.f;
    unsigned gbase[4];
    #pragma unroll
    for (int r = 0; r < 4; ++r) {
        const int sq = seq0 + quad * 4 + r;
        const int bb = sq / NOTES_;
        const int nn = sq - bb * NOTES_;
        gbase[r] = ((unsigned)bb * (T_ * NOTES_) + (unsigned)nn) * 8u + (unsigned)m16;
    }

    // ---- per-lane biases for column j (folded into accX init) ----
    float bg4[4];
    #pragma unroll
    for (int g = 0; g < 4; ++g) bg4[g] = bih[g * H_ + j] + bhh[g * H_ + j];

    // ---- x A-fragment pointers (lane m16 -> sequence row) ----
    const float* xrf = XB16 ? nullptr
        : ((const float*)xin + (size_t)(seq0 + m16) * T_ * IN_);
    const unsigned short* xrb = XB16
        ? ((const unsigned short*)xin + (size_t)(seq0 + m16) * T_ * IN_) : nullptr;

    short8 ax0, ax1, ax2 = zero8;
    // load x(0)
    if (XB16) {
        const unsigned short* p = xrb;
        ax0 = *(const short8*)(p + quad * 8);
        ax1 = *(const short8*)(p + 32 + quad * 8);
        if (quad < 2) ax2 = *(const short8*)(p + 64 + quad * 8);
    } else {
        const float* p = xrf;
        ax0 = pack8(p + quad * 8);
        ax1 = pack8(p + 32 + quad * 8);
        if (quad < 2) ax2 = pack8(p + 64 + quad * 8);
    }

    // prologue: accX(0) = bias + x(0).Wih^T
    f32x4 accX[4];
    #pragma unroll
    for (int g = 0; g < 4; ++g) {
        accX[g] = (f32x4){bg4[g], bg4[g], bg4[g], bg4[g]};
        accX[g] = __builtin_amdgcn_mfma_f32_16x16x32_bf16(ax0, wf[g][0], accX[g], 0, 0, 0);
        accX[g] = __builtin_amdgcn_mfma_f32_16x16x32_bf16(ax1, wf[g][1], accX[g], 0, 0, 0);
        accX[g] = __builtin_amdgcn_mfma_f32_16x16x32_bf16(ax2, wf[g][2], accX[g], 0, 0, 0);
    }
    // load x(1)
    if (XB16) {
        const unsigned short* p = xrb + IN_;
        ax0 = *(const short8*)(p + quad * 8);
        ax1 = *(const short8*)(p + 32 + quad * 8);
        if (quad < 2) ax2 = *(const short8*)(p + 64 + quad * 8);
    } else {
        const float* p = xrf + IN_;
        ax0 = pack8(p + quad * 8);
        ax1 = pack8(p + 32 + quad * 8);
        if (quad < 2) ax2 = pack8(p + 64 + quad * 8);
    }

    float cst[4] = {0.f, 0.f, 0.f, 0.f};       // cell state, in-register

    __syncthreads();                            // init fence (once; full drain ok)

    for (int t = 0; t < T_; ++t) {
        const unsigned short* sHr = sH[t & 1];          // holds h(t-1)
        unsigned short*       sHw = sH[(t & 1) ^ 1];    // receives h(t)

        // h(t-1) A-fragments first: LDS latency starts before any compute
        short8 ah[4];
        #pragma unroll
        for (int kt = 0; kt < 4; ++kt)
            ah[kt] = *(const short8*)(sHr + m16 * SHSTR + kt * 32 + quad * 8);

        // main gate MFMAs: start from accX (bias + x-part), 4-deep h chain
        f32x4 acc[4];
        __builtin_amdgcn_s_setprio(1);
        #pragma unroll
        for (int g = 0; g < 4; ++g) {
            acc[g] = accX[g];
            #pragma unroll
            for (int kt = 0; kt < 4; ++kt)
                acc[g] = __builtin_amdgcn_mfma_f32_16x16x32_bf16(ah[kt], hf[g][kt], acc[g], 0, 0, 0);
        }
        __builtin_amdgcn_s_setprio(0);

        if (grpB) {
            // B order: matrix filler first, then VALU
            ACCX_AND_PREFETCH
            CELL_AND_H_WRITE
            GN_TILE
        } else {
            // A order: VALU first, matrix filler last
            CELL_AND_H_WRITE
            GN_TILE
            ACCX_AND_PREFETCH
        }

        // ONE barrier per step; double-buffered sH makes it race-free.
        // sched_barrier pins ds ops around the asm waitcnt (guide rule #18).
        __builtin_amdgcn_sched_barrier(0);
        asm volatile("s_waitcnt lgkmcnt(0)" ::: "memory");
        __builtin_amdgcn_s_barrier();
        __builtin_amdgcn_sched_barrier(0);
    }

    // epilogue: note-gate tile for t = T-1 (h(127) sits in sH[0])
    if (wave == ((T_ - 1) & 7)) {
        const unsigned short* sHr = sH[T_ & 1];
        short8 ah[4];
        #pragma unroll
        for (int kt = 0; kt < 4; ++kt)
            ah[kt] = *(const short8*)(sHr + m16 * SHSTR + kt * 32 + quad * 8);
        f32x4 an = (f32x4){0.f, 0.f, 0.f, 0.f};
        #pragma unroll
        for (int kt = 0; kt < 4; ++kt)
            an = __builtin_amdgcn_mfma_f32_16x16x32_bf16(ah[kt], wn[kt], an, 0, 0, 0);
        if (m16 < 8) {
            #pragma unroll
            for (int r = 0; r < 4; ++r)
                Gn[gbase[r] + (unsigned)(T_ - 1) * (NOTES_ * 8)] = an[r] + bns;
        }
    }
}

// ---------------------------------------------------------------------------
// Note-LSTM recurrence on precomputed pre-activations.
// One thread per (b,t) sequence.  Gate order g: 0,1=i 2,3=f 4,5=g 6,7=o.
// ---------------------------------------------------------------------------
__global__ __launch_bounds__(64) void note_out_kernel(
    const float* __restrict__ Gn,    // [SEQ2_][NOTES][8] f32
    const float* __restrict__ Whh,   // [8][2] f32
    float* __restrict__ out)         // [B][T][156] f32
{
    const int q = blockIdx.x * 64 + threadIdx.x;
    if (q >= SEQ2_) return;

    float w0[8], w1[8];
    #pragma unroll
    for (int g = 0; g < 8; ++g) { w0[g] = Whh[g * 2]; w1[g] = Whh[g * 2 + 1]; }

    const float* gp = Gn + (size_t)q * (NOTES_ * 8);
    float* op = out + (size_t)q * (NOTES_ * 2);

    float h0 = 0.f, h1 = 0.f, c0 = 0.f, c1 = 0.f;
    f32x4 ga = *(const f32x4*)(gp);
    f32x4 gb = *(const f32x4*)(gp + 4);
    for (int n = 0; n < NOTES_; ++n) {
        f32x4 na, nb;
        if (n + 1 < NOTES_) {
            na = *(const f32x4*)(gp + (n + 1) * 8);
            nb = *(const f32x4*)(gp + (n + 1) * 8 + 4);
        }
        const float i0 = ga[0] + w0[0] * h0 + w1[0] * h1;
        const float i1 = ga[1] + w0[1] * h0 + w1[1] * h1;
        const float f0 = ga[2] + w0[2] * h0 + w1[2] * h1;
        const float f1 = ga[3] + w0[3] * h0 + w1[3] * h1;
        const float g0 = gb[0] + w0[4] * h0 + w1[4] * h1;
        const float g1 = gb[1] + w0[5] * h0 + w1[5] * h1;
        const float o0 = gb[2] + w0[6] * h0 + w1[6] * h1;
        const float o1 = gb[3] + w0[7] * h0 + w1[7] * h1;
        c0 = sigm(f0) * c0 + sigm(i0) * tanhr(g0);
        c1 = sigm(f1) * c1 + sigm(i1) * tanhr(g1);
        h0 = sigm(o0) * tanhr(c0);
        h1 = sigm(o1) * tanhr(c1);
        op[n * 2 + 0] = h0;
        op[n * 2 + 1] = h1;
        ga = na; gb = nb;
    }
}

extern "C" void kernel_launch(void* const* d_in, const int* in_sizes, int n_in,
                              void* d_out, int out_size, void* d_ws, size_t ws_size,
                              hipStream_t stream) {
    const float* x     = (const float*)d_in[0];
    const float* Wih_t = (const float*)d_in[1];
    const float* Whh_t = (const float*)d_in[2];
    const float* bih_t = (const float*)d_in[3];
    const float* bhh_t = (const float*)d_in[4];
    const float* Wih_n = (const float*)d_in[5];
    const float* Whh_n = (const float*)d_in[6];
    const float* bih_n = (const float*)d_in[7];
    const float* bhh_n = (const float*)d_in[8];
    float* out = (float*)d_out;

    const size_t xb_bytes = (size_t)NSEQ_ * T_ * IN_ * 2;          // 51.1 MB
    const size_t gn_bytes = (size_t)SEQ2_ * NOTES_ * 8 * 4;        // 10.2 MB

    if (ws_size >= xb_bytes + gn_bytes) {
        // Layout: [xb16 51.1MB][Gn 10.2MB]
        unsigned short* xb = (unsigned short*)d_ws;
        float* Gn = (float*)((char*)d_ws + xb_bytes);
        xcvt_kernel<<<(XN8 + 255) / 256, 256, 0, stream>>>(x, xb);
        time_lstm_kernel<true><<<NBLK1, 512, 0, stream>>>(
            xb, Wih_t, Whh_t, bih_t, bhh_t, Wih_n, bih_n, bhh_n, Gn);
        note_out_kernel<<<SEQ2_ / 64, 64, 0, stream>>>(Gn, Whh_n, out);
    } else {
        // Fallback: no x pre-convert; Gn at ws base.
        float* Gn = (float*)d_ws;
        time_lstm_kernel<false><<<NBLK1, 512, 0, stream>>>(
            x, Wih_t, Whh_t, bih_t, bhh_t, Wih_n, bih_n, bhh_n, Gn);
        note_out_kernel<<<SEQ2_ / 64, 64, 0, stream>>>(Gn, Whh_n, out);
    }
}